// Round 9
// baseline (145.139 us; speedup 1.0000x reference)
//
#include <hip/hip_runtime.h>
#include <hip/hip_bf16.h>
#include <math.h>

// ---------------------------------------------------------------------------
// Metric loss (lifted structure) on MI355X — R12: resubmit of R11 (infra
// failure last round; container died before any measurement; kernel audit
// found no hang vector).
// Design (R11): 2 tiles/block, fused 16-step counted-vmcnt pipeline.
// Evidence: R8 says marginal warm Gram pass = 11.85us chip-wide, yet
// egemm_1x ~48us -> ~35us is PER-BLOCK serial overhead (prologue staging
// ramp, epilogue transcendentals+shuffles, barrier+atomic drain) paid 1176x
// at ~2.2 blocks/CU with a second dispatch batch (1176 > 768 resident).
// R12: grid 588, each block runs tiles {2b, 2b+1} as ONE 16-step pipeline:
// tile1's first stages issue at g=6,7 (under tile0 compute); tile0's
// epilogue + tile1 sq loads run at the g=8 boundary under tile1's in-flight
// stages. Halves per-block fixed cost, single resident batch, hides tile1
// prologue. (Change vs R11: 16-step loop not force-unrolled — vmcnt
// immediates stay compile-time via the g==8||g==15 branch; buffer indices
// may be runtime for both gload_lds dest and ds_read addr.)
// prep/loss unchanged from R7.
// ---------------------------------------------------------------------------

typedef __bf16 bf16x8 __attribute__((ext_vector_type(8)));
typedef float floatx4 __attribute__((ext_vector_type(4)));

#define KD 256
#define NU 6144
#define NBU 48
#define TU (NBU * (NBU + 1) / 2) /* 1176 */
#define BM 128
#define BK 32
#define ECONST 2.718281828459045f

// logical (row r, 16B k-slot q) -> bf16 element index in swizzled LDS tile
#define LSLOT(r, q) ((((r) * 4 + ((q) ^ (((r) >> 1) & 3)))) * 8)

__device__ __forceinline__ void gload_lds16(const void* g, void* l) {
  __builtin_amdgcn_global_load_lds((const __attribute__((address_space(1))) unsigned int*)g,
                                   (__attribute__((address_space(3))) unsigned int*)l,
                                   16, 0, 0);
}

// ---- prep: bf16 convert unique rows, row sq from bf16; zero accums + out ---
__global__ __launch_bounds__(256) void prep_kernel(const float* __restrict__ text,
                                                   const float* __restrict__ shape,
                                                   __bf16* __restrict__ Xu,
                                                   float* __restrict__ sq,
                                                   float* __restrict__ rowacc,
                                                   float* __restrict__ out, int out_n) {
  int gt = blockIdx.x * 256 + threadIdx.x;
  if (gt < 2 * NU) rowacc[gt] = 0.f;  // St ++ Ss contiguous
  if (gt < out_n) out[gt] = 0.f;      // loss kernel atomicAdds into out[0]
  int wave = gt >> 6;                 // one wave per unique row, 0..6143
  int lane = gt & 63;
  const float* src = (wave < 4096) ? (text + (size_t)wave * KD)
                                   : (shape + (size_t)(wave - 4096) * KD);
  // one float4 per lane = the whole 256-float row per wave
  float4 v = ((const float4*)src)[lane];
  __bf16 h0 = (__bf16)v.x, h1 = (__bf16)v.y, h2 = (__bf16)v.z, h3 = (__bf16)v.w;
  union { __bf16 h[4]; ushort2 u2[2]; } pk;
  pk.h[0] = h0; pk.h[1] = h1; pk.h[2] = h2; pk.h[3] = h3;
  ((ushort2*)(Xu + (size_t)wave * KD))[lane * 2] = pk.u2[0];
  ((ushort2*)(Xu + (size_t)wave * KD))[lane * 2 + 1] = pk.u2[1];
  // square the ROUNDED values (consistency with MFMA G)
  float f0 = (float)h0, f1 = (float)h1, f2 = (float)h2, f3 = (float)h3;
  float s = f0 * f0 + f1 * f1 + f2 * f2 + f3 * f3;
#pragma unroll
  for (int m = 1; m < 64; m <<= 1) s += __shfl_xor(s, m, 64);
  if (lane == 0) sq[wave] = s;
}

// ---- per-tile epilogue: E = exp(1-D), diag-free row/col sums, atomics ------
__device__ __forceinline__ void tile_epilogue(
    const floatx4 (&acc)[4][4], const float (&sqr)[4][4], const float (&sqc)[4],
    bool diag, int mBase, int nBase, int by, int bx, int tid, int quad, int l15,
    int warpM, int warpN, float (*rowbuf)[128], float (*colbuf)[128],
    float* __restrict__ rowacc) {
  const float L2E = 1.44269504088896f;
  float cs[4] = {0.f, 0.f, 0.f, 0.f};
#pragma unroll
  for (int tm = 0; tm < 4; ++tm) {
    float rs[4] = {0.f, 0.f, 0.f, 0.f};
#pragma unroll
    for (int tn = 0; tn < 4; ++tn) {
#pragma unroll
      for (int r = 0; r < 4; ++r) {
        float v = acc[tm][tn][r];
        float dsq = fmaf(-2.0f, v, sqr[tm][r] + sqc[tn]);
        float dst = sqrtf(fmaxf(dsq, 0.f));
        float ev = __builtin_amdgcn_exp2f(fmaf(-L2E, dst, L2E));
        // unique-level diagonal excluded (handled analytically downstream)
        if (diag && tm == tn && (quad * 4 + r) == l15) ev = 0.f;
        rs[r] += ev;
        cs[tn] += ev;
      }
    }
#pragma unroll
    for (int r = 0; r < 4; ++r) {
      float v = rs[r];
      v += __shfl_xor(v, 1, 64);
      v += __shfl_xor(v, 2, 64);
      v += __shfl_xor(v, 4, 64);
      v += __shfl_xor(v, 8, 64);
      if (l15 == 0) rowbuf[warpN][warpM * 64 + tm * 16 + quad * 4 + r] = v;
    }
  }
#pragma unroll
  for (int tn = 0; tn < 4; ++tn) {
    float v = cs[tn];
    v += __shfl_xor(v, 16, 64);
    v += __shfl_xor(v, 32, 64);
    if (quad == 0) colbuf[warpM][warpN * 64 + tn * 16 + l15] = v;
  }
  __syncthreads();
  // rows -> St if cols are text (bx<32) else Ss; cols -> St if rows text
  float* rdst = rowacc + (bx < 32 ? 0 : NU);
  float* cdst = rowacc + (by < 32 ? 0 : NU);
  if (tid < 128) {
    atomicAdd(&rdst[mBase + tid], rowbuf[0][tid] + rowbuf[1][tid]);
  } else if (!diag) {
    int c = tid - 128;
    atomicAdd(&cdst[nBase + c], colbuf[0][c] + colbuf[1][c]);
  }
}

// ---- triangular Gram: 2 tiles per block, one fused 16-step pipeline --------
// (256,3): 170-VGPR cap; LDS 50KB -> 3 blocks/CU; 588 blocks all resident.
__global__ __launch_bounds__(256, 3) void egemm_tri_kernel(
    const __bf16* __restrict__ X, const float* __restrict__ sq,
    float* __restrict__ rowacc) {  // [0,NU)=St, [NU,2NU)=Ss
  __shared__ __align__(16) __bf16 As[3][BM * BK];
  __shared__ __align__(16) __bf16 Bs[3][BM * BK];
  __shared__ float rowbuf[2][128];
  __shared__ float colbuf[2][128];

  // triangular decode of tile0 (= 2*bid); tile1 = tile0+1 derived directly
  const int t0 = blockIdx.x * 2;
  int by0 = (int)((sqrtf(8.0f * (float)t0 + 1.0f) - 1.0f) * 0.5f);
  while ((by0 + 1) * (by0 + 2) / 2 <= t0) ++by0;
  while (by0 * (by0 + 1) / 2 > t0) --by0;
  const int bx0 = t0 - by0 * (by0 + 1) / 2;
  int by1, bx1;
  if (bx0 < by0) { by1 = by0; bx1 = bx0 + 1; }
  else           { by1 = by0 + 1; bx1 = 0;   }

  const int mB0 = by0 * BM, nB0 = bx0 * BM;
  const int mB1 = by1 * BM, nB1 = bx1 * BM;
  const bool dg0 = (by0 == bx0), dg1 = (by1 == bx1);

  const int tid = threadIdx.x;
  const int lane = tid & 63;
  const int w = tid >> 6;  // 2x2 wave grid of 64x64 tiles
  const int warpM = w >> 1, warpN = w & 1;
  const int quad = lane >> 4;
  const int l15 = lane & 15;
  // staging: chunk c (16 rows, 1KB); lane L -> row 16c+(L>>2), swizzled k-slot
  const int sRow = lane >> 2;
  const int sCol = (((lane & 3) ^ ((lane >> 3) & 3))) * 8;

  // tile0 sq loads (issued early; drained by first vmcnt or compiler waits)
  float sqr0[4][4], sqc0[4], sqr1[4][4], sqc1[4];
  {
    const int rb = mB0 + warpM * 64, cb = nB0 + warpN * 64;
#pragma unroll
    for (int tm = 0; tm < 4; ++tm)
#pragma unroll
      for (int r = 0; r < 4; ++r) sqr0[tm][r] = sq[rb + tm * 16 + quad * 4 + r];
#pragma unroll
    for (int tn = 0; tn < 4; ++tn) sqc0[tn] = sq[cb + tn * 16 + l15];
  }

  floatx4 acc[4][4] = {};

#define STAGE(buf, MB, NB, kt)                                                         \
  {                                                                                    \
    _Pragma("unroll") for (int h = 0; h < 2; ++h) {                                    \
      int c = h * 4 + w;                                                               \
      gload_lds16(X + (size_t)((MB) + c * 16 + sRow) * KD + (kt) + sCol,               \
                  &As[buf][c * 512]);                                                  \
      gload_lds16(X + (size_t)((NB) + c * 16 + sRow) * KD + (kt) + sCol,               \
                  &Bs[buf][c * 512]);                                                  \
    }                                                                                  \
  }

  STAGE(0, mB0, nB0, 0);
  STAGE(1, mB0, nB0, BK);

  // Fused pipeline: steps g=0..7 = tile0, g=8..15 = tile1. Stage for step
  // g+2 targets buf (g+2)%3, whose last reader was step g-1 (guaranteed done
  // by barrier(g)). Tile1's first stages issue at g=6,7 under tile0 compute.
  // Epilogue(tile0) + tile1 sq loads run at the g=8 boundary; the explicit
  // vmcnt(0) at g=8 clears staging AND the epilogue's atomics from the
  // queue before counted waits resume.
  for (int g = 0; g < 16; ++g) {
    if (g == 8) {
      {  // tile1 sq loads: latency hides under epilogue(tile0) VALU
        const int rb = mB1 + warpM * 64, cb = nB1 + warpN * 64;
#pragma unroll
        for (int tm = 0; tm < 4; ++tm)
#pragma unroll
          for (int r = 0; r < 4; ++r) sqr1[tm][r] = sq[rb + tm * 16 + quad * 4 + r];
#pragma unroll
        for (int tn = 0; tn < 4; ++tn) sqc1[tn] = sq[cb + tn * 16 + l15];
      }
      tile_epilogue(acc, sqr0, sqc0, dg0, mB0, nB0, by0, bx0, tid, quad, l15,
                    warpM, warpN, rowbuf, colbuf, rowacc);
#pragma unroll
      for (int tm = 0; tm < 4; ++tm)
#pragma unroll
        for (int tn = 0; tn < 4; ++tn)
#pragma unroll
          for (int r = 0; r < 4; ++r) acc[tm][tn][r] = 0.f;
    }
    if (g == 8 || g == 15)
      asm volatile("s_waitcnt vmcnt(0)" ::: "memory");
    else
      asm volatile("s_waitcnt vmcnt(4)" ::: "memory");
    __builtin_amdgcn_s_barrier();
    asm volatile("" ::: "memory");
    if (g + 2 < 8) {
      STAGE((g + 2) % 3, mB0, nB0, (g + 2) * BK);
    } else if (g + 2 < 16) {
      STAGE((g + 2) % 3, mB1, nB1, ((g + 2) & 7) * BK);
    }

    const int cur = g % 3;
    bf16x8 af[4], bfr[4];
#pragma unroll
    for (int tm = 0; tm < 4; ++tm)
      af[tm] = *(const bf16x8*)&As[cur][LSLOT(warpM * 64 + tm * 16 + l15, quad)];
#pragma unroll
    for (int tn = 0; tn < 4; ++tn)
      bfr[tn] = *(const bf16x8*)&Bs[cur][LSLOT(warpN * 64 + tn * 16 + l15, quad)];
#pragma unroll
    for (int tm = 0; tm < 4; ++tm)
#pragma unroll
      for (int tn = 0; tn < 4; ++tn)
        acc[tm][tn] = __builtin_amdgcn_mfma_f32_16x16x32_bf16(af[tm], bfr[tn], acc[tm][tn], 0, 0, 0);
  }
#undef STAGE

  tile_epilogue(acc, sqr1, sqc1, dg1, mB1, nB1, by1, bx1, tid, quad, l15,
                warpM, warpN, rowbuf, colbuf, rowacc);
}

// ---- per-pair fp32 distance + analytic ns + J; atomicAdd into out[0] -------
// 768 blocks x 4 waves, 2 pairs per wave (6144 pairs total).
__global__ __launch_bounds__(256) void loss_kernel(const float* __restrict__ text,
                                                   const float* __restrict__ shape,
                                                   const float* __restrict__ rowacc,
                                                   float* __restrict__ out) {
  __shared__ float part[4];
  const float* St = rowacc;
  const float* Ss = rowacc + NU;
  const int w = threadIdx.x >> 6;
  const int lane = threadIdx.x & 63;
  float jacc = 0.f;
#pragma unroll
  for (int it = 0; it < 2; ++it) {
    int wv = it * 3072 + blockIdx.x * 4 + w;  // 0..6143, exact cover
    const float *a, *b;
    float base, scale;
    if (wv < 2048) {  // tt pair p
      int p = wv;
      a = text + (size_t)(2 * p) * KD;
      b = text + (size_t)(2 * p + 1) * KD;
      base = St[2 * p] + St[2 * p + 1];
      scale = 1.0f / 4096.0f;
    } else {  // st pair
      int p = wv - 2048;
      int u1, u2;
      if (p < 2048) {  // (text_2p, shape_p)
        u1 = 2 * p; u2 = 4096 + p;
        a = text + (size_t)(2 * p) * KD;
        b = shape + (size_t)p * KD;
      } else {         // (shape_s, text_{2s+1})
        int s = p - 2048;
        u1 = 4096 + s; u2 = 2 * s + 1;
        a = shape + (size_t)s * KD;
        b = text + (size_t)(2 * s + 1) * KD;
      }
      float g1 = St[u1] + 2.0f * Ss[u1];
      float g2 = St[u2] + 2.0f * Ss[u2];
      base = g1 + g2 + ECONST;
      scale = 1.0f / 8192.0f;
    }
    // one float4 per lane = whole 256-float row per wave
    float4 va = ((const float4*)a)[lane];
    float4 vb = ((const float4*)b)[lane];
    float d0 = va.x - vb.x, d1 = va.y - vb.y, d2 = va.z - vb.z, d3 = va.w - vb.w;
    float s = d0 * d0 + d1 * d1 + d2 * d2 + d3 * d3;
#pragma unroll
    for (int m = 1; m < 64; m <<= 1) s += __shfl_xor(s, m, 64);
    if (lane == 0) {
      float D = s > 0.f ? sqrtf(s) : 0.f;
      float ns = base - 2.0f * expf(1.0f - D);
      float J = logf(ns) + D;
      jacc += (J > 0.f) ? J * J * scale : 0.f;
    }
  }
  if (lane == 0) part[w] = jacc;
  __syncthreads();
  if (threadIdx.x == 0) atomicAdd(out, part[0] + part[1] + part[2] + part[3]);
}

extern "C" void kernel_launch(void* const* d_in, const int* in_sizes, int n_in,
                              void* d_out, int out_size, void* d_ws, size_t ws_size,
                              hipStream_t stream) {
  const float* text = (const float*)d_in[0];
  const float* shape = (const float*)d_in[1];
  float* out = (float*)d_out;

  char* ws = (char*)d_ws;
  __bf16* Xu = (__bf16*)ws;                                // 3 MB
  float* sq = (float*)(ws + (size_t)NU * KD * 2);          // 24 KB
  float* rowacc = sq + NU;                                 // 48 KB (St ++ Ss)

  prep_kernel<<<NU / 4, 256, 0, stream>>>(text, shape, Xu, sq, rowacc, out, out_size);
  egemm_tri_kernel<<<TU / 2, 256, 0, stream>>>(Xu, sq, rowacc);
  loss_kernel<<<768, 256, 0, stream>>>(text, shape, rowacc, out);
}

// Round 10
// 102.237 us; speedup vs baseline: 1.4196x; 1.4196x over previous
//
#include <hip/hip_runtime.h>
#include <hip/hip_bf16.h>
#include <math.h>

// ---------------------------------------------------------------------------
// Metric loss (lifted structure) on MI355X — R13: spill-free 2-tile egemm.
// R12 post-mortem: un-unrolling the 16-step loop (runtime %3 indices +
// in-loop branch around acc's live range) spilled the 64-VGPR accumulator
// to scratch: WRITE_SIZE 63MB / FETCH 56MB (~2x60MB spill-fill), VGPR count
// 84, egemm 75us. Guide rule #20. R13 restores fully-static indexing:
// TWO explicitly-unrolled 8-step segments with tile0's epilogue between
// them; identical pipeline semantics to R11 (tile1 stages issue at segment
// A's g=6,7; tile1 sq loads issue before epilogue-A and hide under its
// VALU; counted vmcnt(4) everywhere except the final drain).
// Per-wave vmcnt ledger (4 gload_lds per STAGE):
//   segA g: outstanding = step g + step g+1 (+older none) -> vmcnt(4)=drain g
//   epilogue __syncthreads drains all (tile1 steps 8,9 landed; issued 2
//   steps early so latency was covered); atomic adds 1 (older than later
//   stages, swept by any subsequent vmcnt(4)).
//   segB g: newest 4 = stage issued in prev iter -> vmcnt(4) correct;
//   g=7 full drain.
// prep/loss unchanged from R7.
// ---------------------------------------------------------------------------

typedef __bf16 bf16x8 __attribute__((ext_vector_type(8)));
typedef float floatx4 __attribute__((ext_vector_type(4)));

#define KD 256
#define NU 6144
#define NBU 48
#define TU (NBU * (NBU + 1) / 2) /* 1176 */
#define BM 128
#define BK 32
#define ECONST 2.718281828459045f

// logical (row r, 16B k-slot q) -> bf16 element index in swizzled LDS tile
#define LSLOT(r, q) ((((r) * 4 + ((q) ^ (((r) >> 1) & 3)))) * 8)

__device__ __forceinline__ void gload_lds16(const void* g, void* l) {
  __builtin_amdgcn_global_load_lds((const __attribute__((address_space(1))) unsigned int*)g,
                                   (__attribute__((address_space(3))) unsigned int*)l,
                                   16, 0, 0);
}

// ---- prep: bf16 convert unique rows, row sq from bf16; zero accums + out ---
__global__ __launch_bounds__(256) void prep_kernel(const float* __restrict__ text,
                                                   const float* __restrict__ shape,
                                                   __bf16* __restrict__ Xu,
                                                   float* __restrict__ sq,
                                                   float* __restrict__ rowacc,
                                                   float* __restrict__ out, int out_n) {
  int gt = blockIdx.x * 256 + threadIdx.x;
  if (gt < 2 * NU) rowacc[gt] = 0.f;  // St ++ Ss contiguous
  if (gt < out_n) out[gt] = 0.f;      // loss kernel atomicAdds into out[0]
  int wave = gt >> 6;                 // one wave per unique row, 0..6143
  int lane = gt & 63;
  const float* src = (wave < 4096) ? (text + (size_t)wave * KD)
                                   : (shape + (size_t)(wave - 4096) * KD);
  // one float4 per lane = the whole 256-float row per wave
  float4 v = ((const float4*)src)[lane];
  __bf16 h0 = (__bf16)v.x, h1 = (__bf16)v.y, h2 = (__bf16)v.z, h3 = (__bf16)v.w;
  union { __bf16 h[4]; ushort2 u2[2]; } pk;
  pk.h[0] = h0; pk.h[1] = h1; pk.h[2] = h2; pk.h[3] = h3;
  ((ushort2*)(Xu + (size_t)wave * KD))[lane * 2] = pk.u2[0];
  ((ushort2*)(Xu + (size_t)wave * KD))[lane * 2 + 1] = pk.u2[1];
  // square the ROUNDED values (consistency with MFMA G)
  float f0 = (float)h0, f1 = (float)h1, f2 = (float)h2, f3 = (float)h3;
  float s = f0 * f0 + f1 * f1 + f2 * f2 + f3 * f3;
#pragma unroll
  for (int m = 1; m < 64; m <<= 1) s += __shfl_xor(s, m, 64);
  if (lane == 0) sq[wave] = s;
}

// ---- per-tile epilogue: E = exp(1-D), diag-free row/col sums, atomics ------
__device__ __forceinline__ void tile_epilogue(
    const floatx4 (&acc)[4][4], const float (&sqr)[4][4], const float (&sqc)[4],
    bool diag, int mBase, int nBase, int by, int bx, int tid, int quad, int l15,
    int warpM, int warpN, float (*rowbuf)[128], float (*colbuf)[128],
    float* __restrict__ rowacc) {
  const float L2E = 1.44269504088896f;
  float cs[4] = {0.f, 0.f, 0.f, 0.f};
#pragma unroll
  for (int tm = 0; tm < 4; ++tm) {
    float rs[4] = {0.f, 0.f, 0.f, 0.f};
#pragma unroll
    for (int tn = 0; tn < 4; ++tn) {
#pragma unroll
      for (int r = 0; r < 4; ++r) {
        float v = acc[tm][tn][r];
        float dsq = fmaf(-2.0f, v, sqr[tm][r] + sqc[tn]);
        float dst = sqrtf(fmaxf(dsq, 0.f));
        float ev = __builtin_amdgcn_exp2f(fmaf(-L2E, dst, L2E));
        // unique-level diagonal excluded (handled analytically downstream)
        if (diag && tm == tn && (quad * 4 + r) == l15) ev = 0.f;
        rs[r] += ev;
        cs[tn] += ev;
      }
    }
#pragma unroll
    for (int r = 0; r < 4; ++r) {
      float v = rs[r];
      v += __shfl_xor(v, 1, 64);
      v += __shfl_xor(v, 2, 64);
      v += __shfl_xor(v, 4, 64);
      v += __shfl_xor(v, 8, 64);
      if (l15 == 0) rowbuf[warpN][warpM * 64 + tm * 16 + quad * 4 + r] = v;
    }
  }
#pragma unroll
  for (int tn = 0; tn < 4; ++tn) {
    float v = cs[tn];
    v += __shfl_xor(v, 16, 64);
    v += __shfl_xor(v, 32, 64);
    if (quad == 0) colbuf[warpM][warpN * 64 + tn * 16 + l15] = v;
  }
  __syncthreads();
  // rows -> St if cols are text (bx<32) else Ss; cols -> St if rows text
  float* rdst = rowacc + (bx < 32 ? 0 : NU);
  float* cdst = rowacc + (by < 32 ? 0 : NU);
  if (tid < 128) {
    atomicAdd(&rdst[mBase + tid], rowbuf[0][tid] + rowbuf[1][tid]);
  } else if (!diag) {
    int c = tid - 128;
    atomicAdd(&cdst[nBase + c], colbuf[0][c] + colbuf[1][c]);
  }
}

// ---- triangular Gram: 2 tiles/block, two unrolled 8-step segments ----------
// (256,3): 170-VGPR cap; LDS 50KB -> 3 blocks/CU; 588 blocks all resident.
__global__ __launch_bounds__(256, 3) void egemm_tri_kernel(
    const __bf16* __restrict__ X, const float* __restrict__ sq,
    float* __restrict__ rowacc) {  // [0,NU)=St, [NU,2NU)=Ss
  __shared__ __align__(16) __bf16 As[3][BM * BK];
  __shared__ __align__(16) __bf16 Bs[3][BM * BK];
  __shared__ float rowbuf[2][128];
  __shared__ float colbuf[2][128];

  // triangular decode of tile0 (= 2*bid); tile1 = tile0+1 derived directly
  const int t0 = blockIdx.x * 2;
  int by0 = (int)((sqrtf(8.0f * (float)t0 + 1.0f) - 1.0f) * 0.5f);
  while ((by0 + 1) * (by0 + 2) / 2 <= t0) ++by0;
  while (by0 * (by0 + 1) / 2 > t0) --by0;
  const int bx0 = t0 - by0 * (by0 + 1) / 2;
  int by1, bx1;
  if (bx0 < by0) { by1 = by0; bx1 = bx0 + 1; }
  else           { by1 = by0 + 1; bx1 = 0;   }

  const int mB0 = by0 * BM, nB0 = bx0 * BM;
  const int mB1 = by1 * BM, nB1 = bx1 * BM;
  const bool dg0 = (by0 == bx0), dg1 = (by1 == bx1);

  const int tid = threadIdx.x;
  const int lane = tid & 63;
  const int w = tid >> 6;  // 2x2 wave grid of 64x64 tiles
  const int warpM = w >> 1, warpN = w & 1;
  const int quad = lane >> 4;
  const int l15 = lane & 15;
  // staging: chunk c (16 rows, 1KB); lane L -> row 16c+(L>>2), swizzled k-slot
  const int sRow = lane >> 2;
  const int sCol = (((lane & 3) ^ ((lane >> 3) & 3))) * 8;

  // tile0 sq loads (latency hidden under prologue staging)
  float sqr0[4][4], sqc0[4], sqr1[4][4], sqc1[4];
  {
    const int rb = mB0 + warpM * 64, cb = nB0 + warpN * 64;
#pragma unroll
    for (int tm = 0; tm < 4; ++tm)
#pragma unroll
      for (int r = 0; r < 4; ++r) sqr0[tm][r] = sq[rb + tm * 16 + quad * 4 + r];
#pragma unroll
    for (int tn = 0; tn < 4; ++tn) sqc0[tn] = sq[cb + tn * 16 + l15];
  }

  floatx4 acc[4][4] = {};

#define STAGE(buf, MB, NB, kt)                                                         \
  {                                                                                    \
    _Pragma("unroll") for (int h = 0; h < 2; ++h) {                                    \
      int c = h * 4 + w;                                                               \
      gload_lds16(X + (size_t)((MB) + c * 16 + sRow) * KD + (kt) + sCol,               \
                  &As[buf][c * 512]);                                                  \
      gload_lds16(X + (size_t)((NB) + c * 16 + sRow) * KD + (kt) + sCol,               \
                  &Bs[buf][c * 512]);                                                  \
    }                                                                                  \
  }

#define COMPUTE(buf)                                                                   \
  {                                                                                    \
    bf16x8 af[4], bfr[4];                                                              \
    _Pragma("unroll") for (int tm = 0; tm < 4; ++tm)                                   \
        af[tm] = *(const bf16x8*)&As[buf][LSLOT(warpM * 64 + tm * 16 + l15, quad)];    \
    _Pragma("unroll") for (int tn = 0; tn < 4; ++tn)                                   \
        bfr[tn] = *(const bf16x8*)&Bs[buf][LSLOT(warpN * 64 + tn * 16 + l15, quad)];   \
    _Pragma("unroll") for (int tm = 0; tm < 4; ++tm)                                   \
      _Pragma("unroll") for (int tn = 0; tn < 4; ++tn)                                 \
          acc[tm][tn] =                                                                \
              __builtin_amdgcn_mfma_f32_16x16x32_bf16(af[tm], bfr[tn], acc[tm][tn],    \
                                                      0, 0, 0);                        \
  }

  STAGE(0, mB0, nB0, 0);
  STAGE(1, mB0, nB0, BK);

  // ---- segment A: tile0 steps 0..7; tile1 steps 8,9 staged at g=6,7 ----
#pragma unroll
  for (int g = 0; g < 8; ++g) {
    asm volatile("s_waitcnt vmcnt(4)" ::: "memory");
    __builtin_amdgcn_s_barrier();
    asm volatile("" ::: "memory");
    if (g < 6) {
      STAGE((g + 2) % 3, mB0, nB0, (g + 2) * BK);
    } else {
      STAGE((g + 2) % 3, mB1, nB1, (g - 6) * BK);  // tile1 k0,k1 -> bufs 2,0
    }
    COMPUTE(g % 3);
  }

  // tile1 sq loads: issue now, latency hides under epilogue-A's VALU
  {
    const int rb = mB1 + warpM * 64, cb = nB1 + warpN * 64;
#pragma unroll
    for (int tm = 0; tm < 4; ++tm)
#pragma unroll
      for (int r = 0; r < 4; ++r) sqr1[tm][r] = sq[rb + tm * 16 + quad * 4 + r];
#pragma unroll
    for (int tn = 0; tn < 4; ++tn) sqc1[tn] = sq[cb + tn * 16 + l15];
  }

  tile_epilogue(acc, sqr0, sqc0, dg0, mB0, nB0, by0, bx0, tid, quad, l15,
                warpM, warpN, rowbuf, colbuf, rowacc);

#pragma unroll
  for (int tm = 0; tm < 4; ++tm)
#pragma unroll
    for (int tn = 0; tn < 4; ++tn)
#pragma unroll
      for (int r = 0; r < 4; ++r) acc[tm][tn][r] = 0.f;

  // ---- segment B: tile1 steps 8..15 (bufs (8+g)%3); stage 10.. at g=0..5 --
#pragma unroll
  for (int g = 0; g < 8; ++g) {
    if (g < 7)
      asm volatile("s_waitcnt vmcnt(4)" ::: "memory");
    else
      asm volatile("s_waitcnt vmcnt(0)" ::: "memory");
    __builtin_amdgcn_s_barrier();
    asm volatile("" ::: "memory");
    if (g < 6) STAGE((g + 10) % 3, mB1, nB1, (g + 2) * BK);
    COMPUTE((g + 8) % 3);
  }

  tile_epilogue(acc, sqr1, sqc1, dg1, mB1, nB1, by1, bx1, tid, quad, l15,
                warpM, warpN, rowbuf, colbuf, rowacc);
#undef STAGE
#undef COMPUTE
}

// ---- per-pair fp32 distance + analytic ns + J; atomicAdd into out[0] -------
// 768 blocks x 4 waves, 2 pairs per wave (6144 pairs total).
__global__ __launch_bounds__(256) void loss_kernel(const float* __restrict__ text,
                                                   const float* __restrict__ shape,
                                                   const float* __restrict__ rowacc,
                                                   float* __restrict__ out) {
  __shared__ float part[4];
  const float* St = rowacc;
  const float* Ss = rowacc + NU;
  const int w = threadIdx.x >> 6;
  const int lane = threadIdx.x & 63;
  float jacc = 0.f;
#pragma unroll
  for (int it = 0; it < 2; ++it) {
    int wv = it * 3072 + blockIdx.x * 4 + w;  // 0..6143, exact cover
    const float *a, *b;
    float base, scale;
    if (wv < 2048) {  // tt pair p
      int p = wv;
      a = text + (size_t)(2 * p) * KD;
      b = text + (size_t)(2 * p + 1) * KD;
      base = St[2 * p] + St[2 * p + 1];
      scale = 1.0f / 4096.0f;
    } else {  // st pair
      int p = wv - 2048;
      int u1, u2;
      if (p < 2048) {  // (text_2p, shape_p)
        u1 = 2 * p; u2 = 4096 + p;
        a = text + (size_t)(2 * p) * KD;
        b = shape + (size_t)p * KD;
      } else {         // (shape_s, text_{2s+1})
        int s = p - 2048;
        u1 = 4096 + s; u2 = 2 * s + 1;
        a = shape + (size_t)s * KD;
        b = text + (size_t)(2 * s + 1) * KD;
      }
      float g1 = St[u1] + 2.0f * Ss[u1];
      float g2 = St[u2] + 2.0f * Ss[u2];
      base = g1 + g2 + ECONST;
      scale = 1.0f / 8192.0f;
    }
    // one float4 per lane = whole 256-float row per wave
    float4 va = ((const float4*)a)[lane];
    float4 vb = ((const float4*)b)[lane];
    float d0 = va.x - vb.x, d1 = va.y - vb.y, d2 = va.z - vb.z, d3 = va.w - vb.w;
    float s = d0 * d0 + d1 * d1 + d2 * d2 + d3 * d3;
#pragma unroll
    for (int m = 1; m < 64; m <<= 1) s += __shfl_xor(s, m, 64);
    if (lane == 0) {
      float D = s > 0.f ? sqrtf(s) : 0.f;
      float ns = base - 2.0f * expf(1.0f - D);
      float J = logf(ns) + D;
      jacc += (J > 0.f) ? J * J * scale : 0.f;
    }
  }
  if (lane == 0) part[w] = jacc;
  __syncthreads();
  if (threadIdx.x == 0) atomicAdd(out, part[0] + part[1] + part[2] + part[3]);
}

extern "C" void kernel_launch(void* const* d_in, const int* in_sizes, int n_in,
                              void* d_out, int out_size, void* d_ws, size_t ws_size,
                              hipStream_t stream) {
  const float* text = (const float*)d_in[0];
  const float* shape = (const float*)d_in[1];
  float* out = (float*)d_out;

  char* ws = (char*)d_ws;
  __bf16* Xu = (__bf16*)ws;                                // 3 MB
  float* sq = (float*)(ws + (size_t)NU * KD * 2);          // 24 KB
  float* rowacc = sq + NU;                                 // 48 KB (St ++ Ss)

  prep_kernel<<<NU / 4, 256, 0, stream>>>(text, shape, Xu, sq, rowacc, out, out_size);
  egemm_tri_kernel<<<TU / 2, 256, 0, stream>>>(Xu, sq, rowacc);
  loss_kernel<<<768, 256, 0, stream>>>(text, shape, rowacc, out);
}